// Round 1
// baseline (124.943 us; speedup 1.0000x reference)
//
#include <hip/hip_runtime.h>
#include <math.h>

// FutureEncoder: B=4, S=2048, D=1024, FUTURE_K=32, fp32 in/out.
// R4: two-pass. Pass 1 converts h -> split bf16 hi/lo planes in workspace
// (one conversion per element, memory-bound). Pass 2 = MFMA banded scores
// (pure loads + 3-product MFMA, no in-loop cvt) + LDS softmax + branchless
// fp32 VALU PV. Falls back to proven single-pass kernel if ws too small.

constexpr int S_CONST = 2048;
constexpr int D = 1024;
constexpr int G = 16;            // tokens per block
constexpr int NTOK = 8192;
constexpr int JW = 48;           // score columns per group (band width 16+32)
constexpr int JP = 49;           // padded stride

typedef short bf16x8 __attribute__((ext_vector_type(8)));
typedef float f32x4  __attribute__((ext_vector_type(4)));

__device__ inline unsigned short f2bf(float x) {       // fp32 -> bf16 RNE
    unsigned u = __builtin_bit_cast(unsigned, x);
    u += 0x7fffu + ((u >> 16) & 1u);
    return (unsigned short)(u >> 16);
}
__device__ inline float bf2f(unsigned short h) {
    unsigned u = ((unsigned)h) << 16;
    return __builtin_bit_cast(float, u);
}

// 8 fp32 -> hi/lo bf16 fragments (split so hi+lo ~ exact)
__device__ inline void cvt8(float4 x0, float4 x1, bf16x8& hi, bf16x8& lo) {
    float xs[8] = {x0.x, x0.y, x0.z, x0.w, x1.x, x1.y, x1.z, x1.w};
    #pragma unroll
    for (int e = 0; e < 8; ++e) {
        unsigned short h = f2bf(xs[e]);
        float hf = bf2f(h);
        unsigned short l = f2bf(xs[e] - hf);
        hi[e] = (short)h;
        lo[e] = (short)l;
    }
}

// ---------------------------------------------------------------------------
// Pass 1: h (fp32, NTOK*D) -> hi/lo bf16 planes. 8 elements per thread.
// ---------------------------------------------------------------------------
__global__ __launch_bounds__(256)
void convert_kernel(const float* __restrict__ h,
                    short* __restrict__ hh,
                    short* __restrict__ hl) {
    const size_t i = ((size_t)blockIdx.x * 256 + threadIdx.x) * 8;
    float4 x0 = *(const float4*)(h + i);
    float4 x1 = *(const float4*)(h + i + 4);
    bf16x8 vh, vl;
    cvt8(x0, x1, vh, vl);
    *(bf16x8*)(hh + i) = vh;
    *(bf16x8*)(hl + i) = vl;
}

// ---------------------------------------------------------------------------
// Pass 2: main kernel, reads precomputed bf16 planes for scores.
// ---------------------------------------------------------------------------
__global__ __launch_bounds__(256, 2)
void future_encoder_pre(const float* __restrict__ h,
                        const short* __restrict__ hh,
                        const short* __restrict__ hl,
                        float* __restrict__ out) {
    __shared__ float sc[4 * G * JP];   // per-wave partial scores [w][m][j]
    __shared__ float wm[G * JP];       // final softmax weights  [i][j]

    // XCD swizzle: contiguous chunk per XCD (512 blocks / 8 XCDs)
    int bid = blockIdx.x, nblk = gridDim.x, lb = bid;
    if ((nblk & 7) == 0) {
        int per = nblk >> 3;
        lb = (bid & 7) * per + (bid >> 3);
    }

    const int tid  = threadIdx.x;
    const int w    = tid >> 6;
    const int lane = tid & 63;
    const int t0   = lb * G;                    // first token of group
    const int s0   = t0 & (S_CONST - 1);        // groups never straddle sequences
    const int jlim = (S_CONST - 2) - s0;        // max valid j (>= 14 always)

    // ---------------- Phase 1: scores via MFMA, wave w owns D-slice ----------
    {
        const int d0   = w * 256;
        const int mrow = lane & 15;             // fragment row (token / f-row)
        const int q8   = (lane >> 4) * 8;       // k-chunk within K=32 step

        const size_t abase = (size_t)(t0 + mrow) * D + d0 + q8;
        const short* aph = hh + abase;
        const short* apl = hl + abase;

        int r0 = min(t0 + 1 +  0 + mrow, NTOK - 1);
        int r1 = min(t0 + 1 + 16 + mrow, NTOK - 1);
        int r2 = min(t0 + 1 + 32 + mrow, NTOK - 1);
        const size_t b0 = (size_t)r0 * D + d0 + q8;
        const size_t b1 = (size_t)r1 * D + d0 + q8;
        const size_t b2 = (size_t)r2 * D + d0 + q8;

        f32x4 acc[3] = {{0,0,0,0},{0,0,0,0},{0,0,0,0}};

        #pragma unroll
        for (int kk = 0; kk < 8; ++kk) {
            const int o = kk * 32;
            bf16x8 ah = *(const bf16x8*)(aph + o);
            bf16x8 al = *(const bf16x8*)(apl + o);

            bf16x8 bh = *(const bf16x8*)(hh + b0 + o);
            bf16x8 bl = *(const bf16x8*)(hl + b0 + o);
            acc[0] = __builtin_amdgcn_mfma_f32_16x16x32_bf16(ah, bh, acc[0], 0, 0, 0);
            acc[0] = __builtin_amdgcn_mfma_f32_16x16x32_bf16(ah, bl, acc[0], 0, 0, 0);
            acc[0] = __builtin_amdgcn_mfma_f32_16x16x32_bf16(al, bh, acc[0], 0, 0, 0);

            bh = *(const bf16x8*)(hh + b1 + o);
            bl = *(const bf16x8*)(hl + b1 + o);
            acc[1] = __builtin_amdgcn_mfma_f32_16x16x32_bf16(ah, bh, acc[1], 0, 0, 0);
            acc[1] = __builtin_amdgcn_mfma_f32_16x16x32_bf16(ah, bl, acc[1], 0, 0, 0);
            acc[1] = __builtin_amdgcn_mfma_f32_16x16x32_bf16(al, bh, acc[1], 0, 0, 0);

            bh = *(const bf16x8*)(hh + b2 + o);
            bl = *(const bf16x8*)(hl + b2 + o);
            acc[2] = __builtin_amdgcn_mfma_f32_16x16x32_bf16(ah, bh, acc[2], 0, 0, 0);
            acc[2] = __builtin_amdgcn_mfma_f32_16x16x32_bf16(ah, bl, acc[2], 0, 0, 0);
            acc[2] = __builtin_amdgcn_mfma_f32_16x16x32_bf16(al, bh, acc[2], 0, 0, 0);
        }

        // C layout: col = lane&15 (f-row within tile), row = (lane>>4)*4 + reg (token)
        #pragma unroll
        for (int t = 0; t < 3; ++t) {
            #pragma unroll
            for (int r = 0; r < 4; ++r) {
                int m = (lane >> 4) * 4 + r;
                int j = t * 16 + (lane & 15);
                sc[(w * G + m) * JP + j] = acc[t][r];
            }
        }
    }
    __syncthreads();

    // ---------------- Phase 1.5: reduce partials + softmax -------------------
    {
        const int i   = tid >> 4;      // token 0..15
        const int sub = tid & 15;      // 16 threads per token (same wave, contiguous)

        float v[3];
        #pragma unroll
        for (int c = 0; c < 3; ++c) {
            int j = sub + c * 16;
            float s = sc[(0 * G + i) * JP + j] + sc[(1 * G + i) * JP + j]
                    + sc[(2 * G + i) * JP + j] + sc[(3 * G + i) * JP + j];
            bool valid = (j >= i) && (j <= i + 31) && (j <= jlim);
            v[c] = valid ? s : -1e9f;
        }
        float mx = fmaxf(v[0], fmaxf(v[1], v[2]));
        #pragma unroll
        for (int d = 1; d < 16; d <<= 1) mx = fmaxf(mx, __shfl_xor(mx, d, 16));

        float e[3];
        float sum = 0.f;
        #pragma unroll
        for (int c = 0; c < 3; ++c) { e[c] = __expf(v[c] - mx); sum += e[c]; }
        #pragma unroll
        for (int d = 1; d < 16; d <<= 1) sum += __shfl_xor(sum, d, 16);

        const bool any = (mx > -5e8f);
        const float inv = any ? (1.0f / sum) : 0.f;
        #pragma unroll
        for (int c = 0; c < 3; ++c) {
            int j = sub + c * 16;
            bool valid = (j >= i) && (j <= i + 31) && (j <= jlim);
            wm[i * JP + j] = valid ? e[c] * inv : 0.f;
        }
    }
    __syncthreads();

    // ---------------- Phase 2: PV in fp32 VALU, branchless, 4 tokens/wave ----
    {
        const int i0   = w * 4;                 // wave's first token
        const int doff = lane * 4;              // 4 interleaved float4 chunks
        const int jhi  = min(min(i0 + 34, JW - 1), jlim);

        float4 a0[4] = {}, a1[4] = {}, a2[4] = {}, a3[4] = {};

        for (int j = i0; j <= jhi; ++j) {
            float w0 = wm[(i0 + 0) * JP + j];
            float w1 = wm[(i0 + 1) * JP + j];
            float w2 = wm[(i0 + 2) * JP + j];
            float w3 = wm[(i0 + 3) * JP + j];
            const float* fp = h + (size_t)(t0 + 1 + j) * D + doff;
            #pragma unroll
            for (int c = 0; c < 4; ++c) {
                float4 f = *(const float4*)(fp + c * 256);
                a0[c].x += w0 * f.x; a0[c].y += w0 * f.y; a0[c].z += w0 * f.z; a0[c].w += w0 * f.w;
                a1[c].x += w1 * f.x; a1[c].y += w1 * f.y; a1[c].z += w1 * f.z; a1[c].w += w1 * f.w;
                a2[c].x += w2 * f.x; a2[c].y += w2 * f.y; a2[c].z += w2 * f.z; a2[c].w += w2 * f.w;
                a3[c].x += w3 * f.x; a3[c].y += w3 * f.y; a3[c].z += w3 * f.z; a3[c].w += w3 * f.w;
            }
        }

        float* o0 = out + (size_t)(t0 + i0) * D + doff;
        #pragma unroll
        for (int c = 0; c < 4; ++c) *(float4*)(o0 + 0 * D + c * 256) = a0[c];
        #pragma unroll
        for (int c = 0; c < 4; ++c) *(float4*)(o0 + 1 * D + c * 256) = a1[c];
        #pragma unroll
        for (int c = 0; c < 4; ++c) *(float4*)(o0 + 2 * D + c * 256) = a2[c];
        #pragma unroll
        for (int c = 0; c < 4; ++c) *(float4*)(o0 + 3 * D + c * 256) = a3[c];
    }
}

// ---------------------------------------------------------------------------
// Fallback: proven single-pass kernel (105.4 us) if workspace is too small.
// ---------------------------------------------------------------------------
__global__ __launch_bounds__(256, 2)
void future_encoder_kernel(const float* __restrict__ h,
                           float* __restrict__ out) {
    __shared__ float sc[4 * G * JP];
    __shared__ float wm[G * JP];

    int bid = blockIdx.x, nblk = gridDim.x, lb = bid;
    if ((nblk & 7) == 0) {
        int per = nblk >> 3;
        lb = (bid & 7) * per + (bid >> 3);
    }

    const int tid  = threadIdx.x;
    const int w    = tid >> 6;
    const int lane = tid & 63;
    const int t0   = lb * G;
    const int s0   = t0 & (S_CONST - 1);
    const int jlim = (S_CONST - 2) - s0;

    {
        const int d0   = w * 256;
        const int mrow = lane & 15;
        const int q8   = (lane >> 4) * 8;

        const float* ap = h + (size_t)(t0 + mrow) * D + d0 + q8;
        const float* bp0; const float* bp1; const float* bp2;
        {
            int r0 = min(t0 + 1 +  0 + mrow, NTOK - 1);
            int r1 = min(t0 + 1 + 16 + mrow, NTOK - 1);
            int r2 = min(t0 + 1 + 32 + mrow, NTOK - 1);
            bp0 = h + (size_t)r0 * D + d0 + q8;
            bp1 = h + (size_t)r1 * D + d0 + q8;
            bp2 = h + (size_t)r2 * D + d0 + q8;
        }

        f32x4 acc[3] = {{0,0,0,0},{0,0,0,0},{0,0,0,0}};

        #pragma unroll
        for (int kk = 0; kk < 8; ++kk) {
            const int o = kk * 32;
            bf16x8 ah, al;
            cvt8(*(const float4*)(ap + o), *(const float4*)(ap + o + 4), ah, al);

            bf16x8 bh, bl;
            cvt8(*(const float4*)(bp0 + o), *(const float4*)(bp0 + o + 4), bh, bl);
            acc[0] = __builtin_amdgcn_mfma_f32_16x16x32_bf16(ah, bh, acc[0], 0, 0, 0);
            acc[0] = __builtin_amdgcn_mfma_f32_16x16x32_bf16(ah, bl, acc[0], 0, 0, 0);
            acc[0] = __builtin_amdgcn_mfma_f32_16x16x32_bf16(al, bh, acc[0], 0, 0, 0);

            cvt8(*(const float4*)(bp1 + o), *(const float4*)(bp1 + o + 4), bh, bl);
            acc[1] = __builtin_amdgcn_mfma_f32_16x16x32_bf16(ah, bh, acc[1], 0, 0, 0);
            acc[1] = __builtin_amdgcn_mfma_f32_16x16x32_bf16(ah, bl, acc[1], 0, 0, 0);
            acc[1] = __builtin_amdgcn_mfma_f32_16x16x32_bf16(al, bh, acc[1], 0, 0, 0);

            cvt8(*(const float4*)(bp2 + o), *(const float4*)(bp2 + o + 4), bh, bl);
            acc[2] = __builtin_amdgcn_mfma_f32_16x16x32_bf16(ah, bh, acc[2], 0, 0, 0);
            acc[2] = __builtin_amdgcn_mfma_f32_16x16x32_bf16(ah, bl, acc[2], 0, 0, 0);
            acc[2] = __builtin_amdgcn_mfma_f32_16x16x32_bf16(al, bh, acc[2], 0, 0, 0);
        }

        #pragma unroll
        for (int t = 0; t < 3; ++t) {
            #pragma unroll
            for (int r = 0; r < 4; ++r) {
                int m = (lane >> 4) * 4 + r;
                int j = t * 16 + (lane & 15);
                sc[(w * G + m) * JP + j] = acc[t][r];
            }
        }
    }
    __syncthreads();

    {
        const int i   = tid >> 4;
        const int sub = tid & 15;

        float v[3];
        #pragma unroll
        for (int c = 0; c < 3; ++c) {
            int j = sub + c * 16;
            float s = sc[(0 * G + i) * JP + j] + sc[(1 * G + i) * JP + j]
                    + sc[(2 * G + i) * JP + j] + sc[(3 * G + i) * JP + j];
            bool valid = (j >= i) && (j <= i + 31) && (j <= jlim);
            v[c] = valid ? s : -1e9f;
        }
        float mx = fmaxf(v[0], fmaxf(v[1], v[2]));
        #pragma unroll
        for (int d = 1; d < 16; d <<= 1) mx = fmaxf(mx, __shfl_xor(mx, d, 16));

        float e[3];
        float sum = 0.f;
        #pragma unroll
        for (int c = 0; c < 3; ++c) { e[c] = __expf(v[c] - mx); sum += e[c]; }
        #pragma unroll
        for (int d = 1; d < 16; d <<= 1) sum += __shfl_xor(sum, d, 16);

        const bool any = (mx > -5e8f);
        const float inv = any ? (1.0f / sum) : 0.f;
        #pragma unroll
        for (int c = 0; c < 3; ++c) {
            int j = sub + c * 16;
            bool valid = (j >= i) && (j <= i + 31) && (j <= jlim);
            wm[i * JP + j] = valid ? e[c] * inv : 0.f;
        }
    }
    __syncthreads();

    {
        const int i0   = w * 4;
        const int doff = lane * 4;
        const int jhi  = min(min(i0 + 34, JW - 1), jlim);

        float4 a0[4] = {}, a1[4] = {}, a2[4] = {}, a3[4] = {};

        for (int j = i0; j <= jhi; ++j) {
            float w0 = wm[(i0 + 0) * JP + j];
            float w1 = wm[(i0 + 1) * JP + j];
            float w2 = wm[(i0 + 2) * JP + j];
            float w3 = wm[(i0 + 3) * JP + j];
            if (w0 + w1 + w2 + w3 != 0.f) {
                const float* fp = h + (size_t)(t0 + 1 + j) * D + doff;
                #pragma unroll
                for (int c = 0; c < 4; ++c) {
                    float4 f = *(const float4*)(fp + c * 256);
                    a0[c].x += w0 * f.x; a0[c].y += w0 * f.y; a0[c].z += w0 * f.z; a0[c].w += w0 * f.w;
                    a1[c].x += w1 * f.x; a1[c].y += w1 * f.y; a1[c].z += w1 * f.z; a1[c].w += w1 * f.w;
                    a2[c].x += w2 * f.x; a2[c].y += w2 * f.y; a2[c].z += w2 * f.z; a2[c].w += w2 * f.w;
                    a3[c].x += w3 * f.x; a3[c].y += w3 * f.y; a3[c].z += w3 * f.z; a3[c].w += w3 * f.w;
                }
            }
        }

        float* o0 = out + (size_t)(t0 + i0) * D + doff;
        #pragma unroll
        for (int c = 0; c < 4; ++c) *(float4*)(o0 + 0 * D + c * 256) = a0[c];
        #pragma unroll
        for (int c = 0; c < 4; ++c) *(float4*)(o0 + 1 * D + c * 256) = a1[c];
        #pragma unroll
        for (int c = 0; c < 4; ++c) *(float4*)(o0 + 2 * D + c * 256) = a2[c];
        #pragma unroll
        for (int c = 0; c < 4; ++c) *(float4*)(o0 + 3 * D + c * 256) = a3[c];
    }
}

extern "C" void kernel_launch(void* const* d_in, const int* in_sizes, int n_in,
                              void* d_out, int out_size, void* d_ws, size_t ws_size,
                              hipStream_t stream) {
    const float* h = (const float*)d_in[0];
    float* out = (float*)d_out;
    const int ntok = in_sizes[0] / D;        // 8192
    const int blocks = ntok / G;             // 512

    const size_t ws_needed = (size_t)NTOK * D * sizeof(short) * 2;  // 32 MiB
    if (d_ws != nullptr && ws_size >= ws_needed) {
        short* hh = (short*)d_ws;
        short* hl = hh + (size_t)NTOK * D;
        const int cvt_blocks = (ntok * D) / (8 * 256);   // 4096
        convert_kernel<<<cvt_blocks, 256, 0, stream>>>(h, hh, hl);
        future_encoder_pre<<<blocks, 256, 0, stream>>>(h, hh, hl, out);
    } else {
        future_encoder_kernel<<<blocks, 256, 0, stream>>>(h, out);
    }
}

// Round 2
// 116.152 us; speedup vs baseline: 1.0757x; 1.0757x over previous
//
#include <hip/hip_runtime.h>
#include <math.h>

// FutureEncoder: B=4, S=2048, D=1024, FUTURE_K=32, fp32 in/out.
// R5: two-pass. Pass 1 converts h -> interleaved split-bf16 plane
// [row][chunk-of-8][hi8|lo8] (one 32B store per thread). Pass 2: 8 waves
// per 16-token group (D-slice 128 per wave for scores), explicit 1-deep
// prefetch in score K-loop and PV j-loop, D-split PV across wave pairs.

constexpr int S_CONST = 2048;
constexpr int D = 1024;
constexpr int G = 16;            // tokens per block
constexpr int NTOK = 8192;
constexpr int JW = 48;           // score columns per group (band width 16+32)
constexpr int JP = 49;           // padded stride
constexpr int NW = 8;            // waves per block

typedef short bf16x8 __attribute__((ext_vector_type(8)));
typedef float f32x4  __attribute__((ext_vector_type(4)));

__device__ inline unsigned short f2bf(float x) {       // fp32 -> bf16 RNE
    unsigned u = __builtin_bit_cast(unsigned, x);
    u += 0x7fffu + ((u >> 16) & 1u);
    return (unsigned short)(u >> 16);
}
__device__ inline float bf2f(unsigned short h) {
    unsigned u = ((unsigned)h) << 16;
    return __builtin_bit_cast(float, u);
}

// 8 fp32 -> hi/lo bf16 fragments (split so hi+lo ~ exact)
__device__ inline void cvt8(float4 x0, float4 x1, bf16x8& hi, bf16x8& lo) {
    float xs[8] = {x0.x, x0.y, x0.z, x0.w, x1.x, x1.y, x1.z, x1.w};
    #pragma unroll
    for (int e = 0; e < 8; ++e) {
        unsigned short h = f2bf(xs[e]);
        float hf = bf2f(h);
        unsigned short l = f2bf(xs[e] - hf);
        hi[e] = (short)h;
        lo[e] = (short)l;
    }
}

// ---------------------------------------------------------------------------
// Pass 1: h (fp32) -> interleaved plane: for element chunk o (mult of 8) of
// row r, hi8 at hp[r*2048 + o*2], lo8 at hp[r*2048 + o*2 + 8].
// One 32B contiguous store per thread.
// ---------------------------------------------------------------------------
__global__ __launch_bounds__(256)
void convert_kernel(const float* __restrict__ h, short* __restrict__ hp) {
    const size_t i = ((size_t)blockIdx.x * 256 + threadIdx.x) * 8;
    float4 x0 = *(const float4*)(h + i);
    float4 x1 = *(const float4*)(h + i + 4);
    bf16x8 vh, vl;
    cvt8(x0, x1, vh, vl);
    *(bf16x8*)(hp + i * 2)     = vh;
    *(bf16x8*)(hp + i * 2 + 8) = vl;
}

// ---------------------------------------------------------------------------
// Pass 2: main kernel. 512 threads = 8 waves per 16-token group.
// ---------------------------------------------------------------------------
__global__ __launch_bounds__(512, 4)
void future_encoder_pre(const float* __restrict__ h,
                        const short* __restrict__ hp,
                        float* __restrict__ out) {
    __shared__ float sc[NW * G * JP];  // per-wave partial scores [w][m][j]
    __shared__ float wm[G * JP];       // final softmax weights  [i][j]

    // XCD swizzle: contiguous chunk per XCD (512 blocks / 8 XCDs)
    int bid = blockIdx.x, nblk = gridDim.x, lb = bid;
    if ((nblk & 7) == 0) {
        int per = nblk >> 3;
        lb = (bid & 7) * per + (bid >> 3);
    }

    const int tid  = threadIdx.x;
    const int w    = tid >> 6;
    const int lane = tid & 63;
    const int t0   = lb * G;                    // first token of group
    const int s0   = t0 & (S_CONST - 1);        // groups never straddle sequences
    const int jlim = (S_CONST - 2) - s0;        // max valid j (>= 14 always)

    // ---------------- Phase 1: scores via MFMA, wave w owns 128-wide D-slice -
    {
        const int d0   = w * 128;
        const int mrow = lane & 15;             // fragment row (token / f-row)
        const int q8   = (lane >> 4) * 8;       // k-chunk within K=32 step
        const int dof  = d0 * 2 + q8 * 2;       // short offset into interleaved row

        const short* A = hp + (size_t)(t0 + mrow) * 2048 + dof;
        int r0 = min(t0 +  1 + mrow, NTOK - 1);
        int r1 = min(t0 + 17 + mrow, NTOK - 1);
        int r2 = min(t0 + 33 + mrow, NTOK - 1);
        const short* B0 = hp + (size_t)r0 * 2048 + dof;
        const short* B1 = hp + (size_t)r1 * 2048 + dof;
        const short* B2 = hp + (size_t)r2 * 2048 + dof;

        f32x4 acc[3] = {{0,0,0,0},{0,0,0,0},{0,0,0,0}};

        #define LD8(p, o) (*(const bf16x8*)((p) + (o)))
        bf16x8 cah = LD8(A,0),  cal = LD8(A,8);
        bf16x8 c0h = LD8(B0,0), c0l = LD8(B0,8);
        bf16x8 c1h = LD8(B1,0), c1l = LD8(B1,8);
        bf16x8 c2h = LD8(B2,0), c2l = LD8(B2,8);

        #pragma unroll
        for (int kk = 0; kk < 4; ++kk) {
            bf16x8 nah, nal, n0h, n0l, n1h, n1l, n2h, n2l;
            if (kk < 3) {                       // prefetch next K-step
                const int o = (kk + 1) * 64;
                nah = LD8(A,o);  nal = LD8(A,o+8);
                n0h = LD8(B0,o); n0l = LD8(B0,o+8);
                n1h = LD8(B1,o); n1l = LD8(B1,o+8);
                n2h = LD8(B2,o); n2l = LD8(B2,o+8);
            }
            acc[0] = __builtin_amdgcn_mfma_f32_16x16x32_bf16(cah, c0h, acc[0], 0, 0, 0);
            acc[0] = __builtin_amdgcn_mfma_f32_16x16x32_bf16(cah, c0l, acc[0], 0, 0, 0);
            acc[0] = __builtin_amdgcn_mfma_f32_16x16x32_bf16(cal, c0h, acc[0], 0, 0, 0);

            acc[1] = __builtin_amdgcn_mfma_f32_16x16x32_bf16(cah, c1h, acc[1], 0, 0, 0);
            acc[1] = __builtin_amdgcn_mfma_f32_16x16x32_bf16(cah, c1l, acc[1], 0, 0, 0);
            acc[1] = __builtin_amdgcn_mfma_f32_16x16x32_bf16(cal, c1h, acc[1], 0, 0, 0);

            acc[2] = __builtin_amdgcn_mfma_f32_16x16x32_bf16(cah, c2h, acc[2], 0, 0, 0);
            acc[2] = __builtin_amdgcn_mfma_f32_16x16x32_bf16(cah, c2l, acc[2], 0, 0, 0);
            acc[2] = __builtin_amdgcn_mfma_f32_16x16x32_bf16(cal, c2h, acc[2], 0, 0, 0);

            if (kk < 3) {
                cah = nah; cal = nal;
                c0h = n0h; c0l = n0l;
                c1h = n1h; c1l = n1l;
                c2h = n2h; c2l = n2l;
            }
        }
        #undef LD8

        // C layout: col = lane&15 (f-row within tile), row = (lane>>4)*4 + reg (token)
        #pragma unroll
        for (int t = 0; t < 3; ++t) {
            #pragma unroll
            for (int r = 0; r < 4; ++r) {
                int m = (lane >> 4) * 4 + r;
                int j = t * 16 + (lane & 15);
                sc[(w * G + m) * JP + j] = acc[t][r];
            }
        }
    }
    __syncthreads();

    // ---------------- Phase 1.5: reduce 8 partials + softmax (waves 0-3) -----
    if (tid < 256) {
        const int i   = tid >> 4;      // token 0..15
        const int sub = tid & 15;      // 16 threads per token

        float v[3];
        #pragma unroll
        for (int c = 0; c < 3; ++c) {
            int j = sub + c * 16;
            float s = 0.f;
            #pragma unroll
            for (int ww = 0; ww < NW; ++ww)
                s += sc[(ww * G + i) * JP + j];
            bool valid = (j >= i) && (j <= i + 31) && (j <= jlim);
            v[c] = valid ? s : -1e9f;
        }
        float mx = fmaxf(v[0], fmaxf(v[1], v[2]));
        #pragma unroll
        for (int d = 1; d < 16; d <<= 1) mx = fmaxf(mx, __shfl_xor(mx, d, 16));

        float e[3];
        float sum = 0.f;
        #pragma unroll
        for (int c = 0; c < 3; ++c) { e[c] = __expf(v[c] - mx); sum += e[c]; }
        #pragma unroll
        for (int d = 1; d < 16; d <<= 1) sum += __shfl_xor(sum, d, 16);

        const bool any = (mx > -5e8f);
        const float inv = any ? (1.0f / sum) : 0.f;
        #pragma unroll
        for (int c = 0; c < 3; ++c) {
            int j = sub + c * 16;
            bool valid = (j >= i) && (j <= i + 31) && (j <= jlim);
            wm[i * JP + j] = valid ? e[c] * inv : 0.f;
        }
    }
    __syncthreads();

    // ---------------- Phase 2: PV fp32 VALU; wave pair splits D --------------
    {
        const int i0   = (w & 3) * 4;           // wave's first token
        const int cc   = (w >> 2) * 2;          // first 256-float chunk
        const int doff = cc * 256 + lane * 4;
        const int jhi  = min(min(i0 + 34, JW - 1), jlim);

        float4 a0[2] = {}, a1[2] = {}, a2[2] = {}, a3[2] = {};

        const float* fp0 = h + (size_t)(t0 + 1 + i0) * D + doff;
        float4 fa = *(const float4*)(fp0);
        float4 fb = *(const float4*)(fp0 + 256);

        #define PVFMA(j_) do {                                                  \
            float w0 = wm[(i0 + 0) * JP + (j_)];                                \
            float w1 = wm[(i0 + 1) * JP + (j_)];                                \
            float w2 = wm[(i0 + 2) * JP + (j_)];                                \
            float w3 = wm[(i0 + 3) * JP + (j_)];                                \
            a0[0].x += w0 * fa.x; a0[0].y += w0 * fa.y; a0[0].z += w0 * fa.z; a0[0].w += w0 * fa.w; \
            a1[0].x += w1 * fa.x; a1[0].y += w1 * fa.y; a1[0].z += w1 * fa.z; a1[0].w += w1 * fa.w; \
            a2[0].x += w2 * fa.x; a2[0].y += w2 * fa.y; a2[0].z += w2 * fa.z; a2[0].w += w2 * fa.w; \
            a3[0].x += w3 * fa.x; a3[0].y += w3 * fa.y; a3[0].z += w3 * fa.z; a3[0].w += w3 * fa.w; \
            a0[1].x += w0 * fb.x; a0[1].y += w0 * fb.y; a0[1].z += w0 * fb.z; a0[1].w += w0 * fb.w; \
            a1[1].x += w1 * fb.x; a1[1].y += w1 * fb.y; a1[1].z += w1 * fb.z; a1[1].w += w1 * fb.w; \
            a2[1].x += w2 * fb.x; a2[1].y += w2 * fb.y; a2[1].z += w2 * fb.z; a2[1].w += w2 * fb.w; \
            a3[1].x += w3 * fb.x; a3[1].y += w3 * fb.y; a3[1].z += w3 * fb.z; a3[1].w += w3 * fb.w; \
        } while (0)

        for (int j = i0; j < jhi; ++j) {
            const float* fn = h + (size_t)(t0 + 2 + j) * D + doff;  // row j+1
            float4 na = *(const float4*)(fn);
            float4 nb = *(const float4*)(fn + 256);
            PVFMA(j);
            fa = na; fb = nb;
        }
        PVFMA(jhi);                              // peeled last iteration
        #undef PVFMA

        float* o0 = out + (size_t)(t0 + i0) * D + doff;
        *(float4*)(o0 + 0 * D)       = a0[0];
        *(float4*)(o0 + 0 * D + 256) = a0[1];
        *(float4*)(o0 + 1 * D)       = a1[0];
        *(float4*)(o0 + 1 * D + 256) = a1[1];
        *(float4*)(o0 + 2 * D)       = a2[0];
        *(float4*)(o0 + 2 * D + 256) = a2[1];
        *(float4*)(o0 + 3 * D)       = a3[0];
        *(float4*)(o0 + 3 * D + 256) = a3[1];
    }
}

// ---------------------------------------------------------------------------
// Fallback: proven single-pass kernel (105.4 us) if workspace is too small.
// ---------------------------------------------------------------------------
__global__ __launch_bounds__(256, 2)
void future_encoder_kernel(const float* __restrict__ h,
                           float* __restrict__ out) {
    __shared__ float sc[4 * G * JP];
    __shared__ float wm[G * JP];

    int bid = blockIdx.x, nblk = gridDim.x, lb = bid;
    if ((nblk & 7) == 0) {
        int per = nblk >> 3;
        lb = (bid & 7) * per + (bid >> 3);
    }

    const int tid  = threadIdx.x;
    const int w    = tid >> 6;
    const int lane = tid & 63;
    const int t0   = lb * G;
    const int s0   = t0 & (S_CONST - 1);
    const int jlim = (S_CONST - 2) - s0;

    {
        const int d0   = w * 256;
        const int mrow = lane & 15;
        const int q8   = (lane >> 4) * 8;

        const float* ap = h + (size_t)(t0 + mrow) * D + d0 + q8;
        const float* bp0; const float* bp1; const float* bp2;
        {
            int r0 = min(t0 + 1 +  0 + mrow, NTOK - 1);
            int r1 = min(t0 + 1 + 16 + mrow, NTOK - 1);
            int r2 = min(t0 + 1 + 32 + mrow, NTOK - 1);
            bp0 = h + (size_t)r0 * D + d0 + q8;
            bp1 = h + (size_t)r1 * D + d0 + q8;
            bp2 = h + (size_t)r2 * D + d0 + q8;
        }

        f32x4 acc[3] = {{0,0,0,0},{0,0,0,0},{0,0,0,0}};

        #pragma unroll
        for (int kk = 0; kk < 8; ++kk) {
            const int o = kk * 32;
            bf16x8 ah, al;
            cvt8(*(const float4*)(ap + o), *(const float4*)(ap + o + 4), ah, al);

            bf16x8 bh, bl;
            cvt8(*(const float4*)(bp0 + o), *(const float4*)(bp0 + o + 4), bh, bl);
            acc[0] = __builtin_amdgcn_mfma_f32_16x16x32_bf16(ah, bh, acc[0], 0, 0, 0);
            acc[0] = __builtin_amdgcn_mfma_f32_16x16x32_bf16(ah, bl, acc[0], 0, 0, 0);
            acc[0] = __builtin_amdgcn_mfma_f32_16x16x32_bf16(al, bh, acc[0], 0, 0, 0);

            cvt8(*(const float4*)(bp1 + o), *(const float4*)(bp1 + o + 4), bh, bl);
            acc[1] = __builtin_amdgcn_mfma_f32_16x16x32_bf16(ah, bh, acc[1], 0, 0, 0);
            acc[1] = __builtin_amdgcn_mfma_f32_16x16x32_bf16(ah, bl, acc[1], 0, 0, 0);
            acc[1] = __builtin_amdgcn_mfma_f32_16x16x32_bf16(al, bh, acc[1], 0, 0, 0);

            cvt8(*(const float4*)(bp2 + o), *(const float4*)(bp2 + o + 4), bh, bl);
            acc[2] = __builtin_amdgcn_mfma_f32_16x16x32_bf16(ah, bh, acc[2], 0, 0, 0);
            acc[2] = __builtin_amdgcn_mfma_f32_16x16x32_bf16(ah, bl, acc[2], 0, 0, 0);
            acc[2] = __builtin_amdgcn_mfma_f32_16x16x32_bf16(al, bh, acc[2], 0, 0, 0);
        }

        #pragma unroll
        for (int t = 0; t < 3; ++t) {
            #pragma unroll
            for (int r = 0; r < 4; ++r) {
                int m = (lane >> 4) * 4 + r;
                int j = t * 16 + (lane & 15);
                sc[(w * G + m) * JP + j] = acc[t][r];
            }
        }
    }
    __syncthreads();

    {
        const int i   = tid >> 4;
        const int sub = tid & 15;

        float v[3];
        #pragma unroll
        for (int c = 0; c < 3; ++c) {
            int j = sub + c * 16;
            float s = sc[(0 * G + i) * JP + j] + sc[(1 * G + i) * JP + j]
                    + sc[(2 * G + i) * JP + j] + sc[(3 * G + i) * JP + j];
            bool valid = (j >= i) && (j <= i + 31) && (j <= jlim);
            v[c] = valid ? s : -1e9f;
        }
        float mx = fmaxf(v[0], fmaxf(v[1], v[2]));
        #pragma unroll
        for (int d = 1; d < 16; d <<= 1) mx = fmaxf(mx, __shfl_xor(mx, d, 16));

        float e[3];
        float sum = 0.f;
        #pragma unroll
        for (int c = 0; c < 3; ++c) { e[c] = __expf(v[c] - mx); sum += e[c]; }
        #pragma unroll
        for (int d = 1; d < 16; d <<= 1) sum += __shfl_xor(sum, d, 16);

        const bool any = (mx > -5e8f);
        const float inv = any ? (1.0f / sum) : 0.f;
        #pragma unroll
        for (int c = 0; c < 3; ++c) {
            int j = sub + c * 16;
            bool valid = (j >= i) && (j <= i + 31) && (j <= jlim);
            wm[i * JP + j] = valid ? e[c] * inv : 0.f;
        }
    }
    __syncthreads();

    {
        const int i0   = w * 4;
        const int doff = lane * 4;
        const int jhi  = min(min(i0 + 34, JW - 1), jlim);

        float4 a0[4] = {}, a1[4] = {}, a2[4] = {}, a3[4] = {};

        for (int j = i0; j <= jhi; ++j) {
            float w0 = wm[(i0 + 0) * JP + j];
            float w1 = wm[(i0 + 1) * JP + j];
            float w2 = wm[(i0 + 2) * JP + j];
            float w3 = wm[(i0 + 3) * JP + j];
            if (w0 + w1 + w2 + w3 != 0.f) {
                const float* fp = h + (size_t)(t0 + 1 + j) * D + doff;
                #pragma unroll
                for (int c = 0; c < 4; ++c) {
                    float4 f = *(const float4*)(fp + c * 256);
                    a0[c].x += w0 * f.x; a0[c].y += w0 * f.y; a0[c].z += w0 * f.z; a0[c].w += w0 * f.w;
                    a1[c].x += w1 * f.x; a1[c].y += w1 * f.y; a1[c].z += w1 * f.z; a1[c].w += w1 * f.w;
                    a2[c].x += w2 * f.x; a2[c].y += w2 * f.y; a2[c].z += w2 * f.z; a2[c].w += w2 * f.w;
                    a3[c].x += w3 * f.x; a3[c].y += w3 * f.y; a3[c].z += w3 * f.z; a3[c].w += w3 * f.w;
                }
            }
        }

        float* o0 = out + (size_t)(t0 + i0) * D + doff;
        #pragma unroll
        for (int c = 0; c < 4; ++c) *(float4*)(o0 + 0 * D + c * 256) = a0[c];
        #pragma unroll
        for (int c = 0; c < 4; ++c) *(float4*)(o0 + 1 * D + c * 256) = a1[c];
        #pragma unroll
        for (int c = 0; c < 4; ++c) *(float4*)(o0 + 2 * D + c * 256) = a2[c];
        #pragma unroll
        for (int c = 0; c < 4; ++c) *(float4*)(o0 + 3 * D + c * 256) = a3[c];
    }
}

extern "C" void kernel_launch(void* const* d_in, const int* in_sizes, int n_in,
                              void* d_out, int out_size, void* d_ws, size_t ws_size,
                              hipStream_t stream) {
    const float* h = (const float*)d_in[0];
    float* out = (float*)d_out;
    const int ntok = in_sizes[0] / D;        // 8192
    const int blocks = ntok / G;             // 512

    const size_t ws_needed = (size_t)NTOK * D * sizeof(short) * 2;  // 32 MiB
    if (d_ws != nullptr && ws_size >= ws_needed) {
        short* hp = (short*)d_ws;
        const int cvt_blocks = (ntok * D) / (8 * 256);   // 4096
        convert_kernel<<<cvt_blocks, 256, 0, stream>>>(h, hp);
        future_encoder_pre<<<blocks, 512, 0, stream>>>(h, hp, out);
    } else {
        future_encoder_kernel<<<blocks, 256, 0, stream>>>(h, out);
    }
}

// Round 3
// 102.909 us; speedup vs baseline: 1.2141x; 1.1287x over previous
//
#include <hip/hip_runtime.h>
#include <math.h>

// FutureEncoder: B=4, S=2048, D=1024, FUTURE_K=32, fp32 in/out.
// R6: single kernel, NO workspace (harness poisons the 256 MiB workspace at
// ~42 us/iter inside the timed region; the two-pass convert bought nothing —
// split-bf16 planes are the same bytes as fp32). 512 threads = 8 waves per
// 16-token group; in-kernel split-bf16 conversion; 1-deep prefetch in the
// score K-loop and the PV j-loop; branchless PV with wave-pair D-split.

constexpr int S_CONST = 2048;
constexpr int D = 1024;
constexpr int G = 16;            // tokens per block
constexpr int NTOK = 8192;
constexpr int JW = 48;           // score columns per group (band width 16+32)
constexpr int JP = 49;           // padded stride
constexpr int NW = 8;            // waves per block

typedef short bf16x8 __attribute__((ext_vector_type(8)));
typedef float f32x4  __attribute__((ext_vector_type(4)));

__device__ inline unsigned short f2bf(float x) {       // fp32 -> bf16 RNE
    unsigned u = __builtin_bit_cast(unsigned, x);
    u += 0x7fffu + ((u >> 16) & 1u);
    return (unsigned short)(u >> 16);
}
__device__ inline float bf2f(unsigned short h) {
    unsigned u = ((unsigned)h) << 16;
    return __builtin_bit_cast(float, u);
}

// 8 fp32 -> hi/lo bf16 fragments (split so hi+lo ~ exact)
__device__ inline void cvt8(float4 x0, float4 x1, bf16x8& hi, bf16x8& lo) {
    float xs[8] = {x0.x, x0.y, x0.z, x0.w, x1.x, x1.y, x1.z, x1.w};
    #pragma unroll
    for (int e = 0; e < 8; ++e) {
        unsigned short h = f2bf(xs[e]);
        float hf = bf2f(h);
        unsigned short l = f2bf(xs[e] - hf);
        hi[e] = (short)h;
        lo[e] = (short)l;
    }
}

__global__ __launch_bounds__(512, 4)
void future_encoder_kernel(const float* __restrict__ h,
                           float* __restrict__ out) {
    __shared__ float sc[NW * G * JP];  // per-wave partial scores [w][m][j] (25 KB)
    __shared__ float wm[G * JP];       // final softmax weights  [i][j]

    // XCD swizzle: contiguous chunk per XCD (512 blocks / 8 XCDs)
    int bid = blockIdx.x, nblk = gridDim.x, lb = bid;
    if ((nblk & 7) == 0) {
        int per = nblk >> 3;
        lb = (bid & 7) * per + (bid >> 3);
    }

    const int tid  = threadIdx.x;
    const int w    = tid >> 6;
    const int lane = tid & 63;
    const int t0   = lb * G;                    // first token of group
    const int s0   = t0 & (S_CONST - 1);        // groups never straddle sequences
    const int jlim = (S_CONST - 2) - s0;        // max valid j (>= 14 always)

    // ---------------- Phase 1: scores via MFMA, wave w owns 128-wide D-slice -
    {
        const int d0   = w * 128;
        const int mrow = lane & 15;             // fragment row (token / f-row)
        const int q8   = (lane >> 4) * 8;       // k-chunk within K=32 step

        const float* A = h + (size_t)(t0 + mrow) * D + d0 + q8;
        int r0 = min(t0 +  1 + mrow, NTOK - 1);
        int r1 = min(t0 + 17 + mrow, NTOK - 1);
        int r2 = min(t0 + 33 + mrow, NTOK - 1);
        const float* B0 = h + (size_t)r0 * D + d0 + q8;
        const float* B1 = h + (size_t)r1 * D + d0 + q8;
        const float* B2 = h + (size_t)r2 * D + d0 + q8;

        f32x4 acc[3] = {{0,0,0,0},{0,0,0,0},{0,0,0,0}};

        // preload kk=0 (8 float4 in flight per lane)
        float4 xa0 = *(const float4*)(A),      xa1 = *(const float4*)(A + 4);
        float4 x00 = *(const float4*)(B0),     x01 = *(const float4*)(B0 + 4);
        float4 x10 = *(const float4*)(B1),     x11 = *(const float4*)(B1 + 4);
        float4 x20 = *(const float4*)(B2),     x21 = *(const float4*)(B2 + 4);

        #pragma unroll
        for (int kk = 0; kk < 4; ++kk) {
            float4 na0, na1, n00, n01, n10, n11, n20, n21;
            if (kk < 3) {                       // prefetch next K-step
                const int o = (kk + 1) * 32;
                na0 = *(const float4*)(A  + o); na1 = *(const float4*)(A  + o + 4);
                n00 = *(const float4*)(B0 + o); n01 = *(const float4*)(B0 + o + 4);
                n10 = *(const float4*)(B1 + o); n11 = *(const float4*)(B1 + o + 4);
                n20 = *(const float4*)(B2 + o); n21 = *(const float4*)(B2 + o + 4);
            }

            bf16x8 ah, al;
            cvt8(xa0, xa1, ah, al);

            bf16x8 bh, bl;
            cvt8(x00, x01, bh, bl);
            acc[0] = __builtin_amdgcn_mfma_f32_16x16x32_bf16(ah, bh, acc[0], 0, 0, 0);
            acc[0] = __builtin_amdgcn_mfma_f32_16x16x32_bf16(ah, bl, acc[0], 0, 0, 0);
            acc[0] = __builtin_amdgcn_mfma_f32_16x16x32_bf16(al, bh, acc[0], 0, 0, 0);

            cvt8(x10, x11, bh, bl);
            acc[1] = __builtin_amdgcn_mfma_f32_16x16x32_bf16(ah, bh, acc[1], 0, 0, 0);
            acc[1] = __builtin_amdgcn_mfma_f32_16x16x32_bf16(ah, bl, acc[1], 0, 0, 0);
            acc[1] = __builtin_amdgcn_mfma_f32_16x16x32_bf16(al, bh, acc[1], 0, 0, 0);

            cvt8(x20, x21, bh, bl);
            acc[2] = __builtin_amdgcn_mfma_f32_16x16x32_bf16(ah, bh, acc[2], 0, 0, 0);
            acc[2] = __builtin_amdgcn_mfma_f32_16x16x32_bf16(ah, bl, acc[2], 0, 0, 0);
            acc[2] = __builtin_amdgcn_mfma_f32_16x16x32_bf16(al, bh, acc[2], 0, 0, 0);

            if (kk < 3) {
                xa0 = na0; xa1 = na1;
                x00 = n00; x01 = n01;
                x10 = n10; x11 = n11;
                x20 = n20; x21 = n21;
            }
        }

        // C layout: col = lane&15 (f-row within tile), row = (lane>>4)*4 + reg (token)
        #pragma unroll
        for (int t = 0; t < 3; ++t) {
            #pragma unroll
            for (int r = 0; r < 4; ++r) {
                int m = (lane >> 4) * 4 + r;
                int j = t * 16 + (lane & 15);
                sc[(w * G + m) * JP + j] = acc[t][r];
            }
        }
    }
    __syncthreads();

    // ---------------- Phase 1.5: reduce 8 partials + softmax (waves 0-3) -----
    if (tid < 256) {
        const int i   = tid >> 4;      // token 0..15
        const int sub = tid & 15;      // 16 threads per token

        float v[3];
        #pragma unroll
        for (int c = 0; c < 3; ++c) {
            int j = sub + c * 16;
            float s = 0.f;
            #pragma unroll
            for (int ww = 0; ww < NW; ++ww)
                s += sc[(ww * G + i) * JP + j];
            bool valid = (j >= i) && (j <= i + 31) && (j <= jlim);
            v[c] = valid ? s : -1e9f;
        }
        float mx = fmaxf(v[0], fmaxf(v[1], v[2]));
        #pragma unroll
        for (int d = 1; d < 16; d <<= 1) mx = fmaxf(mx, __shfl_xor(mx, d, 16));

        float e[3];
        float sum = 0.f;
        #pragma unroll
        for (int c = 0; c < 3; ++c) { e[c] = __expf(v[c] - mx); sum += e[c]; }
        #pragma unroll
        for (int d = 1; d < 16; d <<= 1) sum += __shfl_xor(sum, d, 16);

        const bool any = (mx > -5e8f);
        const float inv = any ? (1.0f / sum) : 0.f;
        #pragma unroll
        for (int c = 0; c < 3; ++c) {
            int j = sub + c * 16;
            bool valid = (j >= i) && (j <= i + 31) && (j <= jlim);
            wm[i * JP + j] = valid ? e[c] * inv : 0.f;
        }
    }
    __syncthreads();

    // ---------------- Phase 2: PV fp32 VALU; wave pair splits D --------------
    {
        const int i0   = (w & 3) * 4;           // wave's first token
        const int cc   = (w >> 2) * 2;          // first 256-float chunk
        const int doff = cc * 256 + lane * 4;
        const int jhi  = min(min(i0 + 34, JW - 1), jlim);

        float4 a0[2] = {}, a1[2] = {}, a2[2] = {}, a3[2] = {};

        const float* fp0 = h + (size_t)(t0 + 1 + i0) * D + doff;
        float4 fa = *(const float4*)(fp0);
        float4 fb = *(const float4*)(fp0 + 256);

        #define PVFMA(j_) do {                                                  \
            float w0 = wm[(i0 + 0) * JP + (j_)];                                \
            float w1 = wm[(i0 + 1) * JP + (j_)];                                \
            float w2 = wm[(i0 + 2) * JP + (j_)];                                \
            float w3 = wm[(i0 + 3) * JP + (j_)];                                \
            a0[0].x += w0 * fa.x; a0[0].y += w0 * fa.y; a0[0].z += w0 * fa.z; a0[0].w += w0 * fa.w; \
            a1[0].x += w1 * fa.x; a1[0].y += w1 * fa.y; a1[0].z += w1 * fa.z; a1[0].w += w1 * fa.w; \
            a2[0].x += w2 * fa.x; a2[0].y += w2 * fa.y; a2[0].z += w2 * fa.z; a2[0].w += w2 * fa.w; \
            a3[0].x += w3 * fa.x; a3[0].y += w3 * fa.y; a3[0].z += w3 * fa.z; a3[0].w += w3 * fa.w; \
            a0[1].x += w0 * fb.x; a0[1].y += w0 * fb.y; a0[1].z += w0 * fb.z; a0[1].w += w0 * fb.w; \
            a1[1].x += w1 * fb.x; a1[1].y += w1 * fb.y; a1[1].z += w1 * fb.z; a1[1].w += w1 * fb.w; \
            a2[1].x += w2 * fb.x; a2[1].y += w2 * fb.y; a2[1].z += w2 * fb.z; a2[1].w += w2 * fb.w; \
            a3[1].x += w3 * fb.x; a3[1].y += w3 * fb.y; a3[1].z += w3 * fb.z; a3[1].w += w3 * fb.w; \
        } while (0)

        for (int j = i0; j < jhi; ++j) {
            const float* fn = h + (size_t)(t0 + 2 + j) * D + doff;  // row j+1
            float4 na = *(const float4*)(fn);
            float4 nb = *(const float4*)(fn + 256);
            PVFMA(j);
            fa = na; fb = nb;
        }
        PVFMA(jhi);                              // peeled last iteration
        #undef PVFMA

        float* o0 = out + (size_t)(t0 + i0) * D + doff;
        *(float4*)(o0 + 0 * D)       = a0[0];
        *(float4*)(o0 + 0 * D + 256) = a0[1];
        *(float4*)(o0 + 1 * D)       = a1[0];
        *(float4*)(o0 + 1 * D + 256) = a1[1];
        *(float4*)(o0 + 2 * D)       = a2[0];
        *(float4*)(o0 + 2 * D + 256) = a2[1];
        *(float4*)(o0 + 3 * D)       = a3[0];
        *(float4*)(o0 + 3 * D + 256) = a3[1];
    }
}

extern "C" void kernel_launch(void* const* d_in, const int* in_sizes, int n_in,
                              void* d_out, int out_size, void* d_ws, size_t ws_size,
                              hipStream_t stream) {
    const float* h = (const float*)d_in[0];
    float* out = (float*)d_out;
    const int ntok = in_sizes[0] / D;        // 8192
    const int blocks = ntok / G;             // 512
    future_encoder_kernel<<<blocks, 512, 0, stream>>>(h, out);
}